// Round 7
// baseline (279.569 us; speedup 1.0000x reference)
//
#include <hip/hip_runtime.h>
#include <hip/hip_bf16.h>
#include <math.h>

typedef __bf16 bf16_t;
typedef __bf16 bf16x8 __attribute__((ext_vector_type(8)));
typedef __bf16 bf16x4 __attribute__((ext_vector_type(4)));
typedef float f32x4 __attribute__((ext_vector_type(4)));

#define QEPS 1e-5

__device__ __forceinline__ void gload_lds16(const void* g, void* l) {
  __builtin_amdgcn_global_load_lds((const __attribute__((address_space(1))) void*)g,
                                   (__attribute__((address_space(3))) void*)l, 16, 0, 0);
}

// exact GELU via A&S 7.1.26 erf (|err| <= 1.5e-7), branchless, v_exp/v_rcp
__device__ __forceinline__ float gelu_exact(float x) {
  float a = x * 0.7071067811865476f;
  float s = fabsf(a);
  float t = __builtin_amdgcn_rcpf(__builtin_fmaf(0.3275911f, s, 1.0f));
  float p = __builtin_fmaf(1.061405429f, t, -1.453152027f);
  p = __builtin_fmaf(p, t, 1.421413741f);
  p = __builtin_fmaf(p, t, -0.284496736f);
  p = __builtin_fmaf(p, t, 0.254829592f);
  p = p * t;
  float e = __expf(-s * s);
  float er = copysignf(__builtin_fmaf(-p, e, 1.0f), a);
  return 0.5f * x * (1.0f + er);
}

// ---- P1: per-block fp64 partial sums of |w| ----
__global__ void reduce_part_kernel(const float* __restrict__ w1, const float* __restrict__ w2,
                                   int n, double* __restrict__ part) {
  const bool second = blockIdx.x >= 256;
  const float* __restrict__ w = second ? w2 : w1;
  const int b = second ? blockIdx.x - 256 : blockIdx.x;
  double s = 0.0;
  const int stride = 256 * 256 * 4;
  for (int i = (b * 256 + threadIdx.x) * 4; i < n; i += stride) {
    float4 v = *(const float4*)(w + i);
    s += (double)fabsf(v.x) + (double)fabsf(v.y) + (double)fabsf(v.z) + (double)fabsf(v.w);
  }
  for (int off = 32; off > 0; off >>= 1)
    s += __shfl_down(s, off, 64);
  __shared__ double ls[4];
  int lane = threadIdx.x & 63, wv = threadIdx.x >> 6;
  if (lane == 0) ls[wv] = s;
  __syncthreads();
  if (threadIdx.x == 0) part[blockIdx.x] = ls[0] + ls[1] + ls[2] + ls[3];
}

// ---- P2: fused quantize(w1,w2) + cast/pad(x) ----
__global__ void prep_kernel(const float* __restrict__ w1, const float* __restrict__ w2,
                            const float* __restrict__ x, const double* __restrict__ part,
                            int nW, long long nxv, bf16_t* __restrict__ q1,
                            bf16_t* __restrict__ q2, bf16_t* __restrict__ xb,
                            double* __restrict__ gammas) {
  const int QB = (nW >> 1) >> 8;      // 4608
  const int tid = threadIdx.x;
  if (blockIdx.x < QB) {
    const int half = QB >> 1;
    const bool second = blockIdx.x >= half;
    double p = part[(second ? 256 : 0) + tid];
    for (int off = 32; off > 0; off >>= 1)
      p += __shfl_down(p, off, 64);
    __shared__ double red[4];
    if ((tid & 63) == 0) red[tid >> 6] = p;
    __syncthreads();
    const double g = (red[0] + red[1] + red[2] + red[3]) / (double)nW + QEPS;
    if (tid == 0 && blockIdx.x == (second ? half : 0)) gammas[second ? 1 : 0] = g;
    const double rg = 1.0 / g;
    const int idx = blockIdx.x * 256 + tid - (second ? (nW >> 2) : 0);
    const float4 v = ((const float4*)(second ? w2 : w1))[idx];
    bf16x4 r;
    r[0] = (bf16_t)(float)fmin(1.0, fmax(-1.0, rint((double)v.x * rg)));
    r[1] = (bf16_t)(float)fmin(1.0, fmax(-1.0, rint((double)v.y * rg)));
    r[2] = (bf16_t)(float)fmin(1.0, fmax(-1.0, rint((double)v.z * rg)));
    r[3] = (bf16_t)(float)fmin(1.0, fmax(-1.0, rint((double)v.w * rg)));
    ((bf16x4*)(second ? q2 : q1))[idx] = r;
  } else {
    long long i = ((long long)(blockIdx.x - QB) * 256 + tid) * 4;
    bf16x4 r;
    if (i < nxv) {
      float4 v = *(const float4*)(x + i);
      r[0] = (bf16_t)v.x; r[1] = (bf16_t)v.y; r[2] = (bf16_t)v.z; r[3] = (bf16_t)v.w;
    } else {
      r[0] = (bf16_t)0.0f; r[1] = (bf16_t)0.0f; r[2] = (bf16_t)0.0f; r[3] = (bf16_t)0.0f;
    }
    *(bf16x4*)(xb + i) = r;
  }
}

// ---- C = A(M x K) * B(N x K)^T, bf16 MFMA 16x16x32, 128x128 tile, BK=64 ----
// Double-buffered LDS K-loop with ONE barrier per iteration: gloads for tile
// n+1 issue before the compute of tile n, so the barrier's vmcnt(0) drain
// waits on loads that have had a full compute phase (~1300 cyc) in flight.
// 1D grid, XCD-chunked tile mapping. Swizzled LDS (chunk ^ (row&7)): 0 conflicts.
// EPI==0: h = bf16(gelu(gamma*acc + bias)); EPI==1: fp32 out, rows < Mvalid.
template <int EPI>
__global__ __launch_bounds__(256, 2)
void gemm_bt_kernel(const bf16_t* __restrict__ A, const bf16_t* __restrict__ B,
                    const float* __restrict__ bias, const double* __restrict__ gptr,
                    void* __restrict__ Cout, int N, int K, int Mvalid, int gx) {
  __shared__ bf16_t sm[2][2][128 * 64];   // [buf][A/B][tile] = 64 KB

  // XCD-chunked tile id
  const int G = gridDim.x;
  const int f = blockIdx.x;
  const int xcd = f & 7;
  const int idx = f >> 3;
  const int q8 = G >> 3, r8 = G & 7;
  const int t = xcd * q8 + (xcd < r8 ? xcd : r8) + idx;
  const int bx = t % gx;
  const int by = t / gx;

  const int tid = threadIdx.x;
  const int lane = tid & 63;
  const int wave = tid >> 6;            // 4 waves, 2x2 regions of 64x64
  const int wr = (wave >> 1) * 64;
  const int wc = (wave & 1) * 64;
  const int row16 = lane & 15;
  const int quad = lane >> 4;

  const size_t Ks = (size_t)K;
  const int cg = (tid & 7) ^ ((tid >> 3) & 7);   // swizzled global 16B chunk
  const bf16_t* gA = A + ((size_t)(by * 128 + (tid >> 3))) * Ks + (size_t)cg * 8;
  const bf16_t* gB = B + ((size_t)(bx * 128 + (tid >> 3))) * Ks + (size_t)cg * 8;
  const int lofs = wave * 512;          // wave-uniform LDS base; builtin adds lane*16B

  f32x4 acc[4][4] = {};

  // prologue: stage tile 0 into buf 0
#pragma unroll
  for (int n = 0; n < 4; n++) {
    gload_lds16(gA + (size_t)(n * 32) * Ks, &sm[0][0][lofs + n * 2048]);
    gload_lds16(gB + (size_t)(n * 32) * Ks, &sm[0][1][lofs + n * 2048]);
  }
  gA += 64;
  gB += 64;
  __syncthreads();

  int p = 0;
  for (int k0 = 0; k0 < K; k0 += 64) {
    if (k0 + 64 < K) {   // stage next tile into the other buffer (no wait here)
#pragma unroll
      for (int n = 0; n < 4; n++) {
        gload_lds16(gA + (size_t)(n * 32) * Ks, &sm[p ^ 1][0][lofs + n * 2048]);
        gload_lds16(gB + (size_t)(n * 32) * Ks, &sm[p ^ 1][1][lofs + n * 2048]);
      }
      gA += 64;
      gB += 64;
    }

    const bf16_t* sA = sm[p][0];
    const bf16_t* sB = sm[p][1];
#pragma unroll
    for (int kk = 0; kk < 2; kk++) {
      bf16x8 afr[4], bfr[4];
      const int swz = ((kk * 4 + quad) ^ (row16 & 7)) * 8;
#pragma unroll
      for (int i = 0; i < 4; i++)
        afr[i] = *(const bf16x8*)&sA[(wr + i * 16 + row16) * 64 + swz];
#pragma unroll
      for (int j = 0; j < 4; j++)
        bfr[j] = *(const bf16x8*)&sB[(wc + j * 16 + row16) * 64 + swz];
#pragma unroll
      for (int i = 0; i < 4; i++)
#pragma unroll
        for (int j = 0; j < 4; j++)
          acc[i][j] = __builtin_amdgcn_mfma_f32_16x16x32_bf16(afr[i], bfr[j], acc[i][j], 0, 0, 0);
    }
    __syncthreads();   // single barrier: readers done with buf p AND buf p^1 loads drained
    p ^= 1;
  }

  const float gamma = (float)gptr[0];
  const int c_base = bx * 128 + wc + row16;    // C/D: col = lane&15
  const int r_base = by * 128 + wr + quad * 4; // row = quad*4 + reg

  if constexpr (EPI == 0) {
    // LDS-staged coalesced bf16 stores (sE aliases buf0-A; main loop done)
    bf16_t* sE = &sm[0][0][0];   // 32 x 136 = 8.5 KB <= 16 KB
    float bv[4];
#pragma unroll
    for (int j = 0; j < 4; j++) bv[j] = bias[c_base + j * 16];
    bf16_t* h = (bf16_t*)Cout;
#pragma unroll
    for (int i = 0; i < 4; i++) {
#pragma unroll
      for (int j = 0; j < 4; j++) {
        const int col = wc + j * 16 + row16;
#pragma unroll
        for (int r = 0; r < 4; r++) {
          const int e = (wave >> 1) * 16 + quad * 4 + r;
          float v = gelu_exact(gamma * acc[i][j][r] + bv[j]);
          sE[e * 136 + col] = (bf16_t)v;
        }
      }
      __syncthreads();
      {
        const int e = tid >> 3, ch = tid & 7;
        const int grow = by * 128 + (e >> 4) * 64 + i * 16 + (e & 15);
        bf16_t* dst = &h[(size_t)grow * N + bx * 128];
        *(bf16x8*)&dst[ch * 8] = *(const bf16x8*)&sE[e * 136 + ch * 8];
        *(bf16x8*)&dst[ch * 8 + 64] = *(const bf16x8*)&sE[e * 136 + ch * 8 + 64];
      }
      __syncthreads();
    }
  } else {
    float* out = (float*)Cout;
#pragma unroll
    for (int j = 0; j < 4; j++) {
      const int col = c_base + j * 16;
      const float bv = bias[col];
#pragma unroll
      for (int i = 0; i < 4; i++) {
#pragma unroll
        for (int r = 0; r < 4; r++) {
          const int row = r_base + i * 16 + r;
          if (row < Mvalid)
            out[(size_t)row * N + col] = gamma * acc[i][j][r] + bv;
        }
      }
    }
  }
}

extern "C" void kernel_launch(void* const* d_in, const int* in_sizes, int n_in,
                              void* d_out, int out_size, void* d_ws, size_t ws_size,
                              hipStream_t stream) {
  const float* x  = (const float*)d_in[0];
  const float* w1 = (const float*)d_in[1];
  const float* b1 = (const float*)d_in[2];
  const float* w2 = (const float*)d_in[3];
  const float* b2 = (const float*)d_in[4];
  float* out = (float*)d_out;

  const int M = 64 * 197;      // 12608
  const int Mpad = 12672;      // 99 * 128
  const int D = 768, H = 3072;
  const int nW = H * D;        // 2359296

  char* ws = (char*)d_ws;
  double* part = (double*)ws;                      // [512] partials: ws[0,4096)
  double* gammas = (double*)(ws + 4096);           // [2] — own cacheline
  bf16_t* xb  = (bf16_t*)(ws + 4096 + 256);        // Mpad x D
  bf16_t* w1q = xb + (size_t)Mpad * D;             // H x D
  bf16_t* w2q = w1q + (size_t)H * D;               // D x H
  bf16_t* hb  = w2q + (size_t)D * H;               // Mpad x H

  reduce_part_kernel<<<512, 256, 0, stream>>>(w1, w2, nW, part);
  const int QB = (nW >> 1) >> 8;                   // 4608
  const int CB = (int)(((long long)Mpad * D / 4) / 256);  // 9504
  prep_kernel<<<QB + CB, 256, 0, stream>>>(w1, w2, x, part, nW, (long long)M * D,
                                           w1q, w2q, xb, gammas);

  const int gy = Mpad / 128;      // 99
  const int gx1 = H / 128;        // 24
  const int gx2 = D / 128;        // 6
  gemm_bt_kernel<0><<<gx1 * gy, 256, 0, stream>>>(xb, w1q, b1, gammas + 0, hb, H, D, M, gx1);
  gemm_bt_kernel<1><<<gx2 * gy, 256, 0, stream>>>(hb, w2q, b2, gammas + 1, out, D, H, M, gx2);
}

// Round 8
// 252.541 us; speedup vs baseline: 1.1070x; 1.1070x over previous
//
#include <hip/hip_runtime.h>
#include <hip/hip_bf16.h>
#include <math.h>

typedef __bf16 bf16_t;
typedef __bf16 bf16x8 __attribute__((ext_vector_type(8)));
typedef float f32x4 __attribute__((ext_vector_type(4)));

#define QEPS 1e-5

__device__ __forceinline__ void gload_lds16(const void* g, void* l) {
  __builtin_amdgcn_global_load_lds((const __attribute__((address_space(1))) void*)g,
                                   (__attribute__((address_space(3))) void*)l, 16, 0, 0);
}

// exact GELU via A&S 7.1.26 erf (|err| <= 1.5e-7), branchless
__device__ __forceinline__ float gelu_exact(float x) {
  float a = x * 0.7071067811865476f;
  float s = fabsf(a);
  float t = __builtin_amdgcn_rcpf(__builtin_fmaf(0.3275911f, s, 1.0f));
  float p = __builtin_fmaf(1.061405429f, t, -1.453152027f);
  p = __builtin_fmaf(p, t, 1.421413741f);
  p = __builtin_fmaf(p, t, -0.284496736f);
  p = __builtin_fmaf(p, t, 0.254829592f);
  p = p * t;
  float e = __expf(-s * s);
  float er = copysignf(__builtin_fmaf(-p, e, 1.0f), a);
  return 0.5f * x * (1.0f + er);
}

// ---- P1: per-block fp64 partial sums of |w| ----
__global__ void reduce_part_kernel(const float* __restrict__ w1, const float* __restrict__ w2,
                                   int n, double* __restrict__ part) {
  const bool second = blockIdx.x >= 256;
  const float* __restrict__ w = second ? w2 : w1;
  const int b = second ? blockIdx.x - 256 : blockIdx.x;
  double s = 0.0;
  const int stride = 256 * 256 * 4;
  for (int i = (b * 256 + threadIdx.x) * 4; i < n; i += stride) {
    float4 v = *(const float4*)(w + i);
    s += (double)fabsf(v.x) + (double)fabsf(v.y) + (double)fabsf(v.z) + (double)fabsf(v.w);
  }
  for (int off = 32; off > 0; off >>= 1)
    s += __shfl_down(s, off, 64);
  __shared__ double ls[4];
  int lane = threadIdx.x & 63, wv = threadIdx.x >> 6;
  if (lane == 0) ls[wv] = s;
  __syncthreads();
  if (threadIdx.x == 0) part[blockIdx.x] = ls[0] + ls[1] + ls[2] + ls[3];
}

// ---- P2: quantize w1,w2 + cast/pad x, all into BLOCKED+SWIZZLED layout ----
// Tile = 128 rows x 32 k-cols bf16 (4096 elems, 8 KB). Within a tile, 16-B
// chunk index (r*4 + slot) holds row r, k-chunk (slot ^ (r&3)) -- i.e. the
// exact image global_load_lds staging produces, so GEMM staging is a pure
// linear copy and frag reads use slot = quad ^ (row&3).
__global__ void prep_kernel(const float* __restrict__ w1, const float* __restrict__ w2,
                            const float* __restrict__ x, const double* __restrict__ part,
                            double* __restrict__ gammas, bf16_t* __restrict__ q1,
                            bf16_t* __restrict__ q2, bf16_t* __restrict__ xb) {
  const int tid = threadIdx.x;
  const int b = blockIdx.x;
  if (b < 2304) {                      // weight quantize: 1152 blocks each
    const bool second = b >= 1152;
    double p = part[(second ? 256 : 0) + tid];
    for (int off = 32; off > 0; off >>= 1)
      p += __shfl_down(p, off, 64);
    __shared__ double red[4];
    if ((tid & 63) == 0) red[tid >> 6] = p;
    __syncthreads();
    const double g = (red[0] + red[1] + red[2] + red[3]) / 2359296.0 + QEPS;
    if (tid == 0 && (b == 0 || b == 1152)) gammas[second ? 1 : 0] = g;
    const double rg = 1.0 / g;
    const int gchunk = (second ? b - 1152 : b) * 256 + tid;
    const int tile = gchunk >> 9, cidx = gchunk & 511;
    const int r = cidx >> 2, slot = cidx & 3, cch = slot ^ (r & 3);
    int row, colbase, C;
    if (second) { C = 3072; row = (tile / 96) * 128 + r; colbase = (tile % 96) * 32 + cch * 8; }
    else        { C = 768;  row = (tile / 24) * 128 + r; colbase = (tile % 24) * 32 + cch * 8; }
    const float* __restrict__ W = second ? w2 : w1;
    const float4 v0 = *(const float4*)(W + (size_t)row * C + colbase);
    const float4 v1 = *(const float4*)(W + (size_t)row * C + colbase + 4);
    bf16x8 o;
    o[0] = (bf16_t)(float)fmin(1.0, fmax(-1.0, rint((double)v0.x * rg)));
    o[1] = (bf16_t)(float)fmin(1.0, fmax(-1.0, rint((double)v0.y * rg)));
    o[2] = (bf16_t)(float)fmin(1.0, fmax(-1.0, rint((double)v0.z * rg)));
    o[3] = (bf16_t)(float)fmin(1.0, fmax(-1.0, rint((double)v0.w * rg)));
    o[4] = (bf16_t)(float)fmin(1.0, fmax(-1.0, rint((double)v1.x * rg)));
    o[5] = (bf16_t)(float)fmin(1.0, fmax(-1.0, rint((double)v1.y * rg)));
    o[6] = (bf16_t)(float)fmin(1.0, fmax(-1.0, rint((double)v1.z * rg)));
    o[7] = (bf16_t)(float)fmin(1.0, fmax(-1.0, rint((double)v1.w * rg)));
    *(bf16x8*)((second ? q2 : q1) + (size_t)gchunk * 8) = o;
  } else {                             // x cast/pad: 4752 blocks
    const int gchunk = (b - 2304) * 256 + tid;
    const int tile = gchunk >> 9, cidx = gchunk & 511;
    const int r = cidx >> 2, slot = cidx & 3, cch = slot ^ (r & 3);
    const int row = (tile / 24) * 128 + r;
    const int colbase = (tile % 24) * 32 + cch * 8;
    bf16x8 o;
    if (row < 12608) {
      const float4 v0 = *(const float4*)(x + (size_t)row * 768 + colbase);
      const float4 v1 = *(const float4*)(x + (size_t)row * 768 + colbase + 4);
      o[0] = (bf16_t)v0.x; o[1] = (bf16_t)v0.y; o[2] = (bf16_t)v0.z; o[3] = (bf16_t)v0.w;
      o[4] = (bf16_t)v1.x; o[5] = (bf16_t)v1.y; o[6] = (bf16_t)v1.z; o[7] = (bf16_t)v1.w;
    } else {
      o = bf16x8{};
    }
    *(bf16x8*)(xb + (size_t)gchunk * 8) = o;
  }
}

// ---- GEMM: C = A(128-row tiles) x B(128-row tiles)^T over blocked operands ----
// Block tile 128 x BN (BN = NJ*32), BK=32, LDS double-buffered, ONE barrier per
// iter; prefetch of tile kt+1 issues before compute of kt so the barrier's
// vmcnt(0) drain is covered by the MFMA phase. Wave tile 64 x (BN/2).
// EPI==0: h tiles (blocked+swizzled bf16) = gelu(gamma*acc + bias)
// EPI==1: fp32 row-major out (stride aux), rows < Mvalid
template <int EPI, int NJ>
__global__ __launch_bounds__(256, (NJ == 8 ? 2 : 3))
void gemm_tiled(const bf16_t* __restrict__ A, const bf16_t* __restrict__ B,
                const float* __restrict__ bias, const double* __restrict__ gptr,
                void* __restrict__ Cout, int nkt, int gx, int Mvalid, int aux) {
  constexpr int BN = NJ * 32;
  constexpr int BTILE = BN * 32;           // B block-tile elems per k-slice
  constexpr int NRTB = BN / 128;           // 128-row tiles per B block-tile
  __shared__ bf16_t sm[2 * 4096 + 2 * BTILE];
  bf16_t* const sA0 = sm;                   // [2][4096]
  bf16_t* const sB0 = sm + 2 * 4096;        // [2][BTILE]

  // XCD-chunked tile id (block f -> XCD f%8, contiguous chunk per XCD)
  const int G = gridDim.x;
  const int f = blockIdx.x;
  const int xcd = f & 7;
  const int idx = f >> 3;
  const int q8 = G >> 3, r8 = G & 7;
  const int t = xcd * q8 + (xcd < r8 ? xcd : r8) + idx;
  const int bx = t % gx;
  const int by = t / gx;

  const int tid = threadIdx.x;
  const int lane = tid & 63;
  const int wave = tid >> 6;               // 2x2 wave grid
  const int wr = (wave >> 1) * 64;
  const int wc = (wave & 1) * (BN / 2);
  const int row16 = lane & 15;
  const int quad = lane >> 4;

  const bf16_t* gA = A + ((size_t)by * nkt) * 4096 + tid * 8;
  const bf16_t* gB0 = B + ((size_t)(bx * NRTB) * nkt) * 4096 + tid * 8;
  const bf16_t* gB1 = (NJ == 8) ? B + ((size_t)(bx * NRTB + 1) * nkt) * 4096 + tid * 8 : nullptr;
  const int lws = wave * 512;              // wave-uniform; builtin adds lane*16B

  f32x4 acc[4][NJ] = {};

  // stage tile 0 into buf 0
  {
    gload_lds16(gA, sA0 + lws);
    gload_lds16(gA + 2048, sA0 + 2048 + lws);
    gload_lds16(gB0, sB0 + lws);
    gload_lds16(gB0 + 2048, sB0 + 2048 + lws);
    if constexpr (NJ == 8) {
      gload_lds16(gB1, sB0 + 4096 + lws);
      gload_lds16(gB1 + 2048, sB0 + 6144 + lws);
    }
    gA += 4096; gB0 += 4096;
    if constexpr (NJ == 8) gB1 += 4096;
  }
  __syncthreads();

  int p = 0;
  const int sw = (quad ^ (row16 & 3)) * 8;
  for (int kt = 0; kt < nkt; kt++) {
    if (kt + 1 < nkt) {                    // prefetch next tile into buf p^1
      bf16_t* dA = sA0 + (p ^ 1) * 4096;
      bf16_t* dB = sB0 + (p ^ 1) * BTILE;
      gload_lds16(gA, dA + lws);
      gload_lds16(gA + 2048, dA + 2048 + lws);
      gload_lds16(gB0, dB + lws);
      gload_lds16(gB0 + 2048, dB + 2048 + lws);
      if constexpr (NJ == 8) {
        gload_lds16(gB1, dB + 4096 + lws);
        gload_lds16(gB1 + 2048, dB + 6144 + lws);
      }
      gA += 4096; gB0 += 4096;
      if constexpr (NJ == 8) gB1 += 4096;
    }
    const bf16_t* sA = sA0 + p * 4096;
    const bf16_t* sB = sB0 + p * BTILE;
    bf16x8 afr[4], bfr[NJ];
#pragma unroll
    for (int i = 0; i < 4; i++)
      afr[i] = *(const bf16x8*)&sA[(wr + i * 16 + row16) * 32 + sw];
#pragma unroll
    for (int j = 0; j < NJ; j++)
      bfr[j] = *(const bf16x8*)&sB[(wc + j * 16 + row16) * 32 + sw];
#pragma unroll
    for (int i = 0; i < 4; i++)
#pragma unroll
      for (int j = 0; j < NJ; j++)
        acc[i][j] = __builtin_amdgcn_mfma_f32_16x16x32_bf16(afr[i], bfr[j], acc[i][j], 0, 0, 0);
    __syncthreads();                       // readers done with p; p^1 loads drained
    p ^= 1;
  }

  const float gamma = (float)gptr[0];

  if constexpr (EPI == 0) {
    // write h in blocked+swizzled tile layout; aux = total k-tiles of h (H/32)
    constexpr int SEW = BN + 8;
    bf16_t* sE = sm;                       // 32*SEW <= sm size
    bf16_t* h = (bf16_t*)Cout;
    float bv[NJ];
#pragma unroll
    for (int j = 0; j < NJ; j++) bv[j] = bias[bx * BN + wc + row16 + j * 16];
    const int ktBase = bx * (BN / 32);
#pragma unroll
    for (int i = 0; i < 4; i++) {
#pragma unroll
      for (int j = 0; j < NJ; j++) {
        const int col = wc + j * 16 + row16;
#pragma unroll
        for (int r = 0; r < 4; r++) {
          const int e = (wave >> 1) * 16 + quad * 4 + r;
          sE[e * SEW + col] = (bf16_t)gelu_exact(gamma * acc[i][j][r] + bv[j]);
        }
      }
      __syncthreads();
      {
        const int e2 = tid >> 3, chb = tid & 7;
        const int r_in = (e2 >> 4) * 64 + i * 16 + (e2 & 15);
#pragma unroll
        for (int cc = 0; cc < BN / 64; cc++) {
          const int c = chb + cc * 8;
          const int kt_o = ktBase + (c >> 2);
          const int slot = (c & 3) ^ (r_in & 3);
          const size_t off = ((size_t)(by * aux + kt_o)) * 4096 + r_in * 32 + slot * 8;
          *(bf16x8*)&h[off] = *(const bf16x8*)&sE[e2 * SEW + c * 8];
        }
      }
      __syncthreads();
    }
  } else {
    float* out = (float*)Cout;             // aux = row stride (=768)
    const int c_base = bx * BN + wc + row16;
    const int r_base = by * 128 + wr + quad * 4;
#pragma unroll
    for (int j = 0; j < NJ; j++) {
      const int col = c_base + j * 16;
      const float bv = bias[col];
#pragma unroll
      for (int i = 0; i < 4; i++) {
#pragma unroll
        for (int r = 0; r < 4; r++) {
          const int row = r_base + i * 16 + r;
          if (row < Mvalid)
            out[(size_t)row * aux + col] = gamma * acc[i][j][r] + bv;
        }
      }
    }
  }
}

extern "C" void kernel_launch(void* const* d_in, const int* in_sizes, int n_in,
                              void* d_out, int out_size, void* d_ws, size_t ws_size,
                              hipStream_t stream) {
  const float* x  = (const float*)d_in[0];
  const float* w1 = (const float*)d_in[1];
  const float* b1 = (const float*)d_in[2];
  const float* w2 = (const float*)d_in[3];
  const float* b2 = (const float*)d_in[4];
  float* out = (float*)d_out;

  const int M = 64 * 197;      // 12608
  const int Mpad = 12672;      // 99 * 128
  const int D = 768, H = 3072;
  const int nW = H * D;        // 2359296

  char* ws = (char*)d_ws;
  double* part = (double*)ws;                      // [512] @ ws[0,4096)
  double* gammas = (double*)(ws + 4096);           // [2] own cacheline
  bf16_t* xb  = (bf16_t*)(ws + 4096 + 256);        // 99x24 tiles
  bf16_t* w1q = xb + (size_t)Mpad * D;             // 24x24 tiles
  bf16_t* w2q = w1q + (size_t)H * D;               // 6x96 tiles
  bf16_t* hb  = w2q + (size_t)D * H;               // 99x96 tiles

  reduce_part_kernel<<<512, 256, 0, stream>>>(w1, w2, nW, part);
  prep_kernel<<<2304 + 4752, 256, 0, stream>>>(w1, w2, x, part, gammas, w1q, w2q, xb);

  // GEMM1: 128x256 blocks, grid 99*12; A=xb(nkt=24), B=w1q -> hb blocked
  gemm_tiled<0, 8><<<99 * 12, 256, 0, stream>>>(xb, w1q, b1, gammas + 0, hb, 24, 12, M, H / 32);
  // GEMM2: 128x128 blocks, grid 99*6; A=hb(nkt=96), B=w2q -> fp32 out
  gemm_tiled<1, 4><<<99 * 6, 256, 0, stream>>>(hb, w2q, b2, gammas + 1, out, 96, 6, M, D);
}